// Round 9
// baseline (146.838 us; speedup 1.0000x reference)
//
#include <hip/hip_runtime.h>
#include <hip/hip_bf16.h>

typedef __attribute__((ext_vector_type(4))) float  f32x4;
typedef __attribute__((ext_vector_type(8))) short  s16x8;

#define D_MODEL 2048
#define SEQ     4096
#define BATCH   4
#define NATOMS  64
#define RANK    6
#define NLAYERS 16
#define NAR     (NATOMS*RANK)     /* 384 */
#define M_TOTAL (BATCH*SEQ)       /* 16384 */

#define ASZ  (64*72)    /* shorts: A buffer (+8 pad) */
#define WSZ  (384*64)   /* shorts: W buffer (linear, gload_lds) */
#define PSTR 392        /* P_lds row stride in shorts */

static __device__ __forceinline__ unsigned short f2bf(float x){
    union { float f; unsigned u; } v; v.f = x;
    unsigned r = (v.u + 0x7FFF + ((v.u >> 16) & 1)) >> 16;
    return (unsigned short)r;
}

static __device__ __forceinline__ void gload_lds16(const void* g, void* l) {
    __builtin_amdgcn_global_load_lds(
        (const __attribute__((address_space(1))) unsigned int*)g,
        (__attribute__((address_space(3))) unsigned int*)l, 16, 0, 0);
}

static __device__ __forceinline__ s16x8 cvt8(f32x4 lo, f32x4 hi) {
    union { s16x8 v; unsigned short s[8]; } u;
    u.s[0] = f2bf(lo.x); u.s[1] = f2bf(lo.y); u.s[2] = f2bf(lo.z); u.s[3] = f2bf(lo.w);
    u.s[4] = f2bf(hi.x); u.s[5] = f2bf(hi.y); u.s[6] = f2bf(hi.z); u.s[7] = f2bf(hi.w);
    return u.v;
}

// ---------------------------------------------------------------------------
// Prep: gather layer slice, cast to bf16, lay out K-contiguous.
//   WbfT[n][d]  (n = a*6+r)   from A[a, l, d, r]
//   BbfT[p][n]                from B[a, l, r, p]
// ---------------------------------------------------------------------------
__global__ void prep_kernel(const float* __restrict__ A,
                            const float* __restrict__ B,
                            const int*   __restrict__ layer_idx,
                            unsigned short* __restrict__ WbfT,
                            unsigned short* __restrict__ BbfT)
{
    const int l = layer_idx[0];
    int idx = blockIdx.x * 256 + threadIdx.x;
    const int total = NAR * D_MODEL;   // 786432
    if (idx < total) {
        int n = idx / D_MODEL, d = idx % D_MODEL;
        int a = n / RANK, r = n % RANK;
        float v = A[((size_t)(a*NLAYERS + l) * D_MODEL + d) * RANK + r];
        WbfT[idx] = f2bf(v);
    } else {
        idx -= total;
        int p = idx / NAR, n = idx % NAR;
        int a = n / RANK, r = n % RANK;
        float v = B[((size_t)(a*NLAYERS + l) * RANK + r) * D_MODEL + p];
        BbfT[idx] = f2bf(v);
    }
}

// ---------------------------------------------------------------------------
// Fused LoRA: per block (256 blocks = 1/CU, 512 threads = 8 waves):
//   Phase 1: P[64][384] = scale * (hidden[64 rows] @ W^T), acc in regs.
//            hidden read ONCE.  W dbuf via gload_lds (XOR-preswizzled
//            source), A reg-staged, counted vmcnt(2) barriers.
//   Phase 2: out[64][2048] = P @ B^T.  NO LDS staging, NO barriers:
//            B fragments direct L2->reg, ping-pong prefetched 1 tile
//            ahead (named bA/bB, 2-unrolled); P read from Pl (read-only).
// ---------------------------------------------------------------------------
__global__ __launch_bounds__(512, 1) void fused_lora(
    const float*          __restrict__ hidden,  // [16384][2048] fp32
    const float*          __restrict__ scales,  // [4][64]
    const unsigned short* __restrict__ WbfT,    // [384][2048] bf16
    const unsigned short* __restrict__ BbfT,    // [2048][384] bf16
    float*                __restrict__ out)     // [16384][2048] fp32
{
    __shared__ __align__(16) char smem[116736];
    unsigned short* Af = (unsigned short*)smem;            // 2*ASZ  (18432 B)
    unsigned short* Wf = (unsigned short*)(smem + 18432);  // 2*WSZ  (98304 B)
    unsigned short* Pl = (unsigned short*)smem;            // 64*392 (50176 B)

    const int m0   = blockIdx.x * 64;
    const int tid  = threadIdx.x;
    const int lane = tid & 63;
    const int w    = tid >> 6;          // 0..7
    const int wr   = w >> 2, wc = w & 3;   // phase1: rows wr*32, cols wc*96

    // ---- phase 1 setup ----
    const int rowA = tid >> 3;          // 0..63
    const int c8A  = tid & 7;           // 0..7
    const float* srcA = hidden + (size_t)(m0 + rowA) * D_MODEL + c8A * 8;

    // W staging: 48 gload_lds of 1KB; wave w does insts i = w*6+j.
    // inst i, lane l -> LDS row r = i*8+(l>>3), chunk c = l&7 (16B);
    // source pre-swizzled: LDS chunk c holds global chunk c^(r&7).
    const unsigned short* srcW[6];
    int ldsW[6];
    #pragma unroll
    for (int j = 0; j < 6; ++j) {
        int i = w * 6 + j;
        int r = i * 8 + (lane >> 3);
        int c = (lane & 7) ^ (r & 7);
        srcW[j] = WbfT + (size_t)r * D_MODEL + c * 8;
        ldsW[j] = i * 512;   // shorts
    }

    f32x4 acc[2][6] = {};
    f32x4 ga[2], gb[2];

    // ---- phase 1 prologue ----
    ga[0] = *reinterpret_cast<const f32x4*>(srcA);
    ga[1] = *reinterpret_cast<const f32x4*>(srcA + 4);
    srcA += 64;
    {
        s16x8 s = cvt8(ga[0], ga[1]);
        *reinterpret_cast<s16x8*>(&Af[rowA * 72 + c8A * 8]) = s;
    }
    #pragma unroll
    for (int j = 0; j < 6; ++j) { gload_lds16(srcW[j], &Wf[ldsW[j]]); srcW[j] += 64; }
    __builtin_amdgcn_sched_barrier(0);
    gb[0] = *reinterpret_cast<const f32x4*>(srcA);          // A(1)
    gb[1] = *reinterpret_cast<const f32x4*>(srcA + 4);
    srcA += 64;
    asm volatile("s_waitcnt vmcnt(2) lgkmcnt(0)" ::: "memory");  // W(0) done, A(1) in flight
    __builtin_amdgcn_s_barrier();

    // ---- phase 1 main loop ----
    auto body = [&](int t, f32x4 (&gI)[2], f32x4 (&gC)[2]) {
        const int buf = t & 1;
        if (t < 31) {
            #pragma unroll
            for (int j = 0; j < 6; ++j) {
                gload_lds16(srcW[j], &Wf[(buf ^ 1) * WSZ + ldsW[j]]);
                srcW[j] += 64;
            }
        }
        __builtin_amdgcn_sched_barrier(0);   // pin: W gloads before A loads
        if (t < 30) {
            gI[0] = *reinterpret_cast<const f32x4*>(srcA);
            gI[1] = *reinterpret_cast<const f32x4*>(srcA + 4);
            srcA += 64;
        }
        const unsigned short* Ar = &Af[buf * ASZ];
        const unsigned short* Wr = &Wf[buf * WSZ];
        #pragma unroll
        for (int kk = 0; kk < 2; ++kk) {
            const int kch = kk * 4 + (lane >> 4);
            s16x8 bfr[6], afr[2];
            #pragma unroll
            for (int ni = 0; ni < 6; ++ni) {
                int br = wc * 96 + ni * 16 + (lane & 15);
                bfr[ni] = *reinterpret_cast<const s16x8*>(
                    &Wr[br * 64 + ((kch ^ (br & 7)) << 3)]);
            }
            #pragma unroll
            for (int mi = 0; mi < 2; ++mi) {
                int ar = wr * 32 + mi * 16 + (lane & 15);
                afr[mi] = *reinterpret_cast<const s16x8*>(
                    &Ar[ar * 72 + kk * 32 + (lane >> 4) * 8]);
            }
            #pragma unroll
            for (int mi = 0; mi < 2; ++mi)
                #pragma unroll
                for (int ni = 0; ni < 6; ++ni)
                    acc[mi][ni] = __builtin_amdgcn_mfma_f32_16x16x32_bf16(
                        afr[mi], bfr[ni], acc[mi][ni], 0, 0, 0);
        }
        if (t < 31) {
            s16x8 s = cvt8(gC[0], gC[1]);
            *reinterpret_cast<s16x8*>(&Af[(buf ^ 1) * ASZ + rowA * 72 + c8A * 8]) = s;
            if (t == 30) asm volatile("s_waitcnt vmcnt(0) lgkmcnt(0)" ::: "memory");
            else         asm volatile("s_waitcnt vmcnt(2) lgkmcnt(0)" ::: "memory");
            __builtin_amdgcn_s_barrier();
        }
    };
    for (int tt = 0; tt < 32; tt += 2) {
        body(tt,     ga, gb);
        body(tt + 1, gb, ga);
    }
    __syncthreads();   // phase-1 LDS reads complete; safe to overwrite with P

    // ---- transition: scale + cvt acc -> P_lds ----
    const int b = m0 >> 12;
    #pragma unroll
    for (int ni = 0; ni < 6; ++ni) {
        int col  = wc * 96 + ni * 16 + (lane & 15);
        float sc = scales[b * NATOMS + col / RANK];
        #pragma unroll
        for (int mi = 0; mi < 2; ++mi) {
            #pragma unroll
            for (int r = 0; r < 4; ++r) {
                int row = wr * 32 + mi * 16 + (lane >> 4) * 4 + r;
                Pl[row * PSTR + col] = f2bf(acc[mi][ni][r] * sc);
            }
        }
    }
    __syncthreads();
    // After this point Pl is read-only: phase 2 has NO barriers.

    // ---- phase 2: out = P @ B^T, B direct L2->reg, barrier-free ----
    const int wr2 = w >> 2, wp = w & 3;   // out rows wr2*32, cols pt*64 + wp*16
    // B-frag base: row p = wp*16 + (lane&15), k-chunk base (lane>>4)*8;
    // frag ks at + ks*32 shorts; tile pt at + pt*64*NAR.
    const unsigned short* srcB2 =
        BbfT + (size_t)(wp * 16 + (lane & 15)) * NAR + (lane >> 4) * 8;
    const unsigned short* PlBase = &Pl[(wr2 * 32 + (lane & 15)) * PSTR + (lane >> 4) * 8];

    s16x8 bA[12], bB[12];
    #pragma unroll
    for (int ks = 0; ks < 12; ++ks)
        bA[ks] = *reinterpret_cast<const s16x8*>(srcB2 + ks * 32);

    auto p2body = [&](int pt, s16x8 (&bC)[12], s16x8 (&bN)[12]) {
        if (pt < 31) {
            const unsigned short* s2 = srcB2 + (size_t)(pt + 1) * 64 * NAR;
            #pragma unroll
            for (int ks = 0; ks < 12; ++ks)
                bN[ks] = *reinterpret_cast<const s16x8*>(s2 + ks * 32);
        }
        f32x4 a2[2] = {};
        #pragma unroll
        for (int ks = 0; ks < 12; ++ks) {
            #pragma unroll
            for (int mi = 0; mi < 2; ++mi) {
                s16x8 pfr = *reinterpret_cast<const s16x8*>(PlBase + mi * 16 * PSTR + ks * 32);
                a2[mi] = __builtin_amdgcn_mfma_f32_16x16x32_bf16(
                    pfr, bC[ks], a2[mi], 0, 0, 0);
            }
        }
        #pragma unroll
        for (int mi = 0; mi < 2; ++mi) {
            #pragma unroll
            for (int r = 0; r < 4; ++r) {
                int row = m0 + wr2 * 32 + mi * 16 + (lane >> 4) * 4 + r;
                int col = pt * 64 + wp * 16 + (lane & 15);
                out[(size_t)row * D_MODEL + col] = a2[mi][r];
            }
        }
    };
    for (int pt = 0; pt < 32; pt += 2) {
        p2body(pt,     bA, bB);
        p2body(pt + 1, bB, bA);
    }
}

extern "C" void kernel_launch(void* const* d_in, const int* in_sizes, int n_in,
                              void* d_out, int out_size, void* d_ws, size_t ws_size,
                              hipStream_t stream)
{
    const float* hidden    = (const float*)d_in[0];
    const float* scales    = (const float*)d_in[1];
    const float* A         = (const float*)d_in[2];
    const float* B         = (const float*)d_in[3];
    const int*   layer_idx = (const int*)d_in[4];
    float* out = (float*)d_out;

    unsigned short* WbfT = (unsigned short*)d_ws;            // [384][2048]
    unsigned short* BbfT = WbfT + (size_t)NAR * D_MODEL;     // [2048][384]

    prep_kernel<<<(2 * NAR * D_MODEL) / 256, 256, 0, stream>>>(A, B, layer_idx, WbfT, BbfT);
    fused_lora<<<M_TOTAL / 64, 512, 0, stream>>>(hidden, scales, WbfT, BbfT, out);
}

// Round 10
// 88.201 us; speedup vs baseline: 1.6648x; 1.6648x over previous
//
#include <hip/hip_runtime.h>
#include <hip/hip_bf16.h>

typedef __attribute__((ext_vector_type(4))) float  f32x4;
typedef __attribute__((ext_vector_type(8))) short  s16x8;

#define D_MODEL 2048
#define SEQ     4096
#define BATCH   4
#define NATOMS  64
#define RANK    6
#define NLAYERS 16
#define NAR     (NATOMS*RANK)     /* 384 */
#define M_TOTAL (BATCH*SEQ)       /* 16384 */

#define ASZ  (64*72)    /* shorts: A buffer (+8 pad) */
#define WSZ  (384*64)   /* shorts: W buffer (linear, gload_lds) */
#define PSTR 392        /* P_lds row stride in shorts */
#define BSZ  (64*384)   /* shorts: one Bt buffer (linear, gload_lds) */

static __device__ __forceinline__ unsigned short f2bf(float x){
    union { float f; unsigned u; } v; v.f = x;
    unsigned r = (v.u + 0x7FFF + ((v.u >> 16) & 1)) >> 16;
    return (unsigned short)r;
}

static __device__ __forceinline__ void gload_lds16(const void* g, void* l) {
    __builtin_amdgcn_global_load_lds(
        (const __attribute__((address_space(1))) unsigned int*)g,
        (__attribute__((address_space(3))) unsigned int*)l, 16, 0, 0);
}

static __device__ __forceinline__ s16x8 cvt8(f32x4 lo, f32x4 hi) {
    union { s16x8 v; unsigned short s[8]; } u;
    u.s[0] = f2bf(lo.x); u.s[1] = f2bf(lo.y); u.s[2] = f2bf(lo.z); u.s[3] = f2bf(lo.w);
    u.s[4] = f2bf(hi.x); u.s[5] = f2bf(hi.y); u.s[6] = f2bf(hi.z); u.s[7] = f2bf(hi.w);
    return u.v;
}

// ---------------------------------------------------------------------------
// Prep: gather layer slice, cast to bf16, lay out K-contiguous.
//   WbfT[n][d]  (n = a*6+r)   from A[a, l, d, r]
//   BbfT[p][n]                from B[a, l, r, p]
// ---------------------------------------------------------------------------
__global__ void prep_kernel(const float* __restrict__ A,
                            const float* __restrict__ B,
                            const int*   __restrict__ layer_idx,
                            unsigned short* __restrict__ WbfT,
                            unsigned short* __restrict__ BbfT)
{
    const int l = layer_idx[0];
    int idx = blockIdx.x * 256 + threadIdx.x;
    const int total = NAR * D_MODEL;   // 786432
    if (idx < total) {
        int n = idx / D_MODEL, d = idx % D_MODEL;
        int a = n / RANK, r = n % RANK;
        float v = A[((size_t)(a*NLAYERS + l) * D_MODEL + d) * RANK + r];
        WbfT[idx] = f2bf(v);
    } else {
        idx -= total;
        int p = idx / NAR, n = idx % NAR;
        int a = n / RANK, r = n % RANK;
        float v = B[((size_t)(a*NLAYERS + l) * RANK + r) * D_MODEL + p];
        BbfT[idx] = f2bf(v);
    }
}

// ---------------------------------------------------------------------------
// Fused LoRA (256 blocks = 1/CU, 512 threads = 8 waves):
//   Phase 1 (unchanged from R8): P[64][384] = scale*(hidden @ W^T) in regs;
//            W dbuf gload_lds + XOR swizzle; A reg-staged; counted vmcnt(2).
//   Phase 2 (new): out[64][2048] = P @ B^T.
//            P-frags REGISTER-RESIDENT (loaded once: 24 reads/wave total).
//            B staged per 64-col tile via gload_lds dbuf, XOR-preswizzled
//            source (rows of 48 chunks, chunk c <- global c^(r&7)).
//            Tile barrier = s_waitcnt vmcnt(8) (gloads drained, this tile's
//            8 stores stay in flight) + s_barrier.
// ---------------------------------------------------------------------------
__global__ __launch_bounds__(512, 1) void fused_lora(
    const float*          __restrict__ hidden,  // [16384][2048] fp32
    const float*          __restrict__ scales,  // [4][64]
    const unsigned short* __restrict__ WbfT,    // [384][2048] bf16
    const unsigned short* __restrict__ BbfT,    // [2048][384] bf16
    float*                __restrict__ out)     // [16384][2048] fp32
{
    __shared__ __align__(16) char smem[148480];
    unsigned short* Af = (unsigned short*)smem;            // 2*ASZ  (18432 B)
    unsigned short* Wf = (unsigned short*)(smem + 18432);  // 2*WSZ  (98304 B)
    unsigned short* Pl = (unsigned short*)smem;            // 64*392 (50176 B)
    unsigned short* Bt = (unsigned short*)(smem + 50176);  // 2*BSZ  (98304 B)

    const int m0   = blockIdx.x * 64;
    const int tid  = threadIdx.x;
    const int lane = tid & 63;
    const int w    = tid >> 6;          // 0..7
    const int wr   = w >> 2, wc = w & 3;   // phase1: rows wr*32, cols wc*96

    // ---- phase 1 setup ----
    const int rowA = tid >> 3;          // 0..63
    const int c8A  = tid & 7;           // 0..7
    const float* srcA = hidden + (size_t)(m0 + rowA) * D_MODEL + c8A * 8;

    // W staging: 48 gload_lds of 1KB; wave w does insts i = w*6+j.
    const unsigned short* srcW[6];
    int ldsW[6];
    #pragma unroll
    for (int j = 0; j < 6; ++j) {
        int i = w * 6 + j;
        int r = i * 8 + (lane >> 3);
        int c = (lane & 7) ^ (r & 7);
        srcW[j] = WbfT + (size_t)r * D_MODEL + c * 8;
        ldsW[j] = i * 512;   // shorts
    }

    f32x4 acc[2][6] = {};
    f32x4 ga[2], gb[2];

    // ---- phase 1 prologue ----
    ga[0] = *reinterpret_cast<const f32x4*>(srcA);
    ga[1] = *reinterpret_cast<const f32x4*>(srcA + 4);
    srcA += 64;
    {
        s16x8 s = cvt8(ga[0], ga[1]);
        *reinterpret_cast<s16x8*>(&Af[rowA * 72 + c8A * 8]) = s;
    }
    #pragma unroll
    for (int j = 0; j < 6; ++j) { gload_lds16(srcW[j], &Wf[ldsW[j]]); srcW[j] += 64; }
    __builtin_amdgcn_sched_barrier(0);
    gb[0] = *reinterpret_cast<const f32x4*>(srcA);          // A(1)
    gb[1] = *reinterpret_cast<const f32x4*>(srcA + 4);
    srcA += 64;
    asm volatile("s_waitcnt vmcnt(2) lgkmcnt(0)" ::: "memory");  // W(0) done, A(1) in flight
    __builtin_amdgcn_s_barrier();

    // ---- phase 1 main loop ----
    auto body = [&](int t, f32x4 (&gI)[2], f32x4 (&gC)[2]) {
        const int buf = t & 1;
        if (t < 31) {
            #pragma unroll
            for (int j = 0; j < 6; ++j) {
                gload_lds16(srcW[j], &Wf[(buf ^ 1) * WSZ + ldsW[j]]);
                srcW[j] += 64;
            }
        }
        __builtin_amdgcn_sched_barrier(0);   // pin: W gloads before A loads
        if (t < 30) {
            gI[0] = *reinterpret_cast<const f32x4*>(srcA);
            gI[1] = *reinterpret_cast<const f32x4*>(srcA + 4);
            srcA += 64;
        }
        const unsigned short* Ar = &Af[buf * ASZ];
        const unsigned short* Wr = &Wf[buf * WSZ];
        #pragma unroll
        for (int kk = 0; kk < 2; ++kk) {
            const int kch = kk * 4 + (lane >> 4);
            s16x8 bfr[6], afr[2];
            #pragma unroll
            for (int ni = 0; ni < 6; ++ni) {
                int br = wc * 96 + ni * 16 + (lane & 15);
                bfr[ni] = *reinterpret_cast<const s16x8*>(
                    &Wr[br * 64 + ((kch ^ (br & 7)) << 3)]);
            }
            #pragma unroll
            for (int mi = 0; mi < 2; ++mi) {
                int ar = wr * 32 + mi * 16 + (lane & 15);
                afr[mi] = *reinterpret_cast<const s16x8*>(
                    &Ar[ar * 72 + kk * 32 + (lane >> 4) * 8]);
            }
            #pragma unroll
            for (int mi = 0; mi < 2; ++mi)
                #pragma unroll
                for (int ni = 0; ni < 6; ++ni)
                    acc[mi][ni] = __builtin_amdgcn_mfma_f32_16x16x32_bf16(
                        afr[mi], bfr[ni], acc[mi][ni], 0, 0, 0);
        }
        if (t < 31) {
            s16x8 s = cvt8(gC[0], gC[1]);
            *reinterpret_cast<s16x8*>(&Af[(buf ^ 1) * ASZ + rowA * 72 + c8A * 8]) = s;
            if (t == 30) asm volatile("s_waitcnt vmcnt(0) lgkmcnt(0)" ::: "memory");
            else         asm volatile("s_waitcnt vmcnt(2) lgkmcnt(0)" ::: "memory");
            __builtin_amdgcn_s_barrier();
        }
    };
    for (int tt = 0; tt < 32; tt += 2) {
        body(tt,     ga, gb);
        body(tt + 1, gb, ga);
    }
    __syncthreads();   // phase-1 LDS reads complete; safe to overwrite with P

    // ---- transition: scale + cvt acc -> P_lds ----
    const int b = m0 >> 12;
    #pragma unroll
    for (int ni = 0; ni < 6; ++ni) {
        int col  = wc * 96 + ni * 16 + (lane & 15);
        float sc = scales[b * NATOMS + col / RANK];
        #pragma unroll
        for (int mi = 0; mi < 2; ++mi) {
            #pragma unroll
            for (int r = 0; r < 4; ++r) {
                int row = wr * 32 + mi * 16 + (lane >> 4) * 4 + r;
                Pl[row * PSTR + col] = f2bf(acc[mi][ni][r] * sc);
            }
        }
    }
    __syncthreads();

    // ---- phase 2 setup ----
    const int wr2 = w >> 2, wp = w & 3;   // out rows wr2*32, cols pt*64 + wp*16

    // P fragments -> registers ONCE (24 ds_reads/wave total)
    s16x8 pf[2][12];
    #pragma unroll
    for (int mi = 0; mi < 2; ++mi)
        #pragma unroll
        for (int ks = 0; ks < 12; ++ks)
            pf[mi][ks] = *reinterpret_cast<const s16x8*>(
                &Pl[(wr2 * 32 + mi * 16 + (lane & 15)) * PSTR + (ks * 4 + (lane >> 4)) * 8]);

    // Bt staging: 64 rows x 384 shorts = 3072 chunks of 16B; 6 gload_lds of
    // 8KB each (512 threads x 16B).  Source pre-swizzled: LDS chunk c of row
    // r holds global chunk c^(r&7)  ->  read applies same XOR (involution).
    const unsigned short* srcB[6];
    int dstB[6];
    #pragma unroll
    for (int j = 0; j < 6; ++j) {
        int g  = j * 512 + tid;
        int rB = g / 48, cB = g % 48;
        srcB[j] = BbfT + (size_t)rB * NAR + (cB ^ (rB & 7)) * 8;
        dstB[j] = g * 8;   // linear LDS short offset
    }
    const int rowB = wp * 16 + (lane & 15);

    // prologue: stage Bt(0)
    #pragma unroll
    for (int j = 0; j < 6; ++j) gload_lds16(srcB[j], &Bt[dstB[j]]);
    asm volatile("s_waitcnt vmcnt(0)" ::: "memory");
    __builtin_amdgcn_s_barrier();

    // ---- phase 2 main loop: 32 p-tiles of 64 cols ----
    for (int pt = 0; pt < 32; ++pt) {
        const int buf = pt & 1;
        // 1. issue Bt(pt+1) gloads (oldest VMEM ops this tile)
        if (pt < 31) {
            #pragma unroll
            for (int j = 0; j < 6; ++j)
                gload_lds16(srcB[j] + (size_t)(pt + 1) * 64 * NAR,
                            &Bt[(buf ^ 1) * BSZ + dstB[j]]);
        }
        __builtin_amdgcn_sched_barrier(0);
        // 2. compute tile pt from Bt[buf] + register pf
        f32x4 a2[2] = {};
        const unsigned short* Br = &Bt[buf * BSZ];
        #pragma unroll
        for (int ks = 0; ks < 12; ++ks) {
            s16x8 bfr = *reinterpret_cast<const s16x8*>(
                &Br[(rowB * 48 + ((ks * 4 + (lane >> 4)) ^ (rowB & 7))) * 8]);
            #pragma unroll
            for (int mi = 0; mi < 2; ++mi)
                a2[mi] = __builtin_amdgcn_mfma_f32_16x16x32_bf16(
                    pf[mi][ks], bfr, a2[mi], 0, 0, 0);
        }
        // 3. store tile pt (8 dwords, coalesced 16-col segments)
        #pragma unroll
        for (int mi = 0; mi < 2; ++mi) {
            #pragma unroll
            for (int r = 0; r < 4; ++r) {
                int row = m0 + wr2 * 32 + mi * 16 + (lane >> 4) * 4 + r;
                int col = pt * 64 + wp * 16 + (lane & 15);
                out[(size_t)row * D_MODEL + col] = a2[mi][r];
            }
        }
        // 4. barrier: gloads (6 oldest) drained; this tile's 8 stores in flight
        if (pt < 31) {
            asm volatile("s_waitcnt vmcnt(8)" ::: "memory");
            __builtin_amdgcn_s_barrier();
        }
    }
}

extern "C" void kernel_launch(void* const* d_in, const int* in_sizes, int n_in,
                              void* d_out, int out_size, void* d_ws, size_t ws_size,
                              hipStream_t stream)
{
    const float* hidden    = (const float*)d_in[0];
    const float* scales    = (const float*)d_in[1];
    const float* A         = (const float*)d_in[2];
    const float* B         = (const float*)d_in[3];
    const int*   layer_idx = (const int*)d_in[4];
    float* out = (float*)d_out;

    unsigned short* WbfT = (unsigned short*)d_ws;            // [384][2048]
    unsigned short* BbfT = WbfT + (size_t)NAR * D_MODEL;     // [2048][384]

    prep_kernel<<<(2 * NAR * D_MODEL) / 256, 256, 0, stream>>>(A, B, layer_idx, WbfT, BbfT);
    fused_lora<<<M_TOTAL / 64, 512, 0, stream>>>(hidden, scales, WbfT, BbfT, out);
}